// Round 17
// baseline (85.287 us; speedup 1.0000x reference)
//
#include <hip/hip_runtime.h>
#include <hip/hip_bf16.h>

#define DD 512
#define NN 8
#define LL0 128
#define LL1 256

// 2 * log2(e): pre-scale so tanh(t) needs only v_exp_f32 (2^x).
#define LOG2E2 2.8853900817779268f

// split-K partial plane stride (floats): 3072 rows x 512 e
#define PSTR ((size_t)3072 * 512)

typedef float f32x4 __attribute__((ext_vector_type(4)));
typedef __bf16 bf16x8 __attribute__((ext_vector_type(8)));

__device__ __forceinline__ float fexp2(float x) {
#if __has_builtin(__builtin_amdgcn_exp2f)
    return __builtin_amdgcn_exp2f(x);
#else
    float r; asm("v_exp_f32 %0, %1" : "=v"(r) : "v"(x)); return r;
#endif
}
__device__ __forceinline__ float frcp(float x) {
#if __has_builtin(__builtin_amdgcn_rcpf)
    return __builtin_amdgcn_rcpf(x);
#else
    float r; asm("v_rcp_f32 %0, %1" : "=v"(r) : "v"(x)); return r;
#endif
}

// fp32 -> bf16 round-to-nearest-even (normals; inputs are well-scaled).
__device__ __forceinline__ unsigned short f2bf(float f) {
    unsigned int u = __float_as_uint(f);
    u += 0x7fffu + ((u >> 16) & 1u);
    return (unsigned short)(u >> 16);
}

// ---------------------------------------------------------------------------
// Kernel 0: convert x|m -> A16[3072][512] bf16, W -> W16[512][1024] bf16.
// [r16 verbatim]
// ---------------------------------------------------------------------------
__global__ __launch_bounds__(256) void cvt_kernel(
    const float* __restrict__ x, const float* __restrict__ m,
    const float* __restrict__ W,
    unsigned short* __restrict__ A16, unsigned short* __restrict__ W16)
{
    size_t i4 = ((size_t)blockIdx.x * 256 + threadIdx.x) * 4;
    const float* src;
    unsigned short* dst;
    if (i4 < (size_t)3072 * 512) {                 // A-part (x then m)
        src = (i4 < (size_t)1024 * 512) ? x + i4 : m + (i4 - (size_t)1024 * 512);
        dst = A16 + i4;
    } else {                                       // W-part
        size_t j = i4 - (size_t)3072 * 512;
        src = W + j; dst = W16 + j;
    }
    float4 v = *(const float4*)src;
    ushort4 o = make_ushort4(f2bf(v.x), f2bf(v.y), f2bf(v.z), f2bf(v.w));
    *(ushort4*)dst = o;
}

// ---------------------------------------------------------------------------
// Kernel 1: MFMA bf16 projection GEMM, split-K=2.  [r16 verbatim]
//   pp[kz][row][e] = sum_{k in half kz} A16[row][k] * W16[e][koff+k]
// 64x64 tile, K-step 64, 4 waves; 68-short row pad (136 B) -> b64 fragment
// reads bank-optimal. Grid (8, 48, 2) = 768 blocks = 3.0/CU exact.
// ---------------------------------------------------------------------------
__global__ __launch_bounds__(256, 3) void mfma_proj_kernel(
    const unsigned short* __restrict__ A16, const unsigned short* __restrict__ W16,
    float* __restrict__ pp)
{
    __shared__ unsigned short As[64][68];
    __shared__ unsigned short Bs[64][68];

    int e0   = blockIdx.x * 64;
    int row0 = blockIdx.y * 64;
    int kb0  = blockIdx.z * 256;       // K-half base
    bool isx = row0 < (NN * LL0);
    int koff = isx ? 0 : DD;

    int tid  = threadIdx.x;
    int wid  = tid >> 6;               // wave 0..3 -> rows wid*16..+15
    int lane = tid & 63;
    int l15  = lane & 15, lk = lane >> 4;   // lk 0..3

    int srow = tid >> 2;               // staging row 0..63
    int scol = (tid & 3) * 16;         // staging k-col (bf16 units)

    const unsigned short* Ap = A16 + (size_t)(row0 + srow) * DD + kb0 + scol;
    const unsigned short* Bp = W16 + (size_t)(e0 + srow) * (2 * DD) + koff + kb0 + scol;

    uint4 a0 = *(const uint4*)(Ap);
    uint4 a1 = *(const uint4*)(Ap + 8);
    uint4 b0 = *(const uint4*)(Bp);
    uint4 b1 = *(const uint4*)(Bp + 8);

    f32x4 acc[4] = {};

    for (int kt = 0; kt < 4; ++kt) {
        if (kt) __syncthreads();
        *(uint2*)&As[srow][scol + 0]  = make_uint2(a0.x, a0.y);
        *(uint2*)&As[srow][scol + 4]  = make_uint2(a0.z, a0.w);
        *(uint2*)&As[srow][scol + 8]  = make_uint2(a1.x, a1.y);
        *(uint2*)&As[srow][scol + 12] = make_uint2(a1.z, a1.w);
        *(uint2*)&Bs[srow][scol + 0]  = make_uint2(b0.x, b0.y);
        *(uint2*)&Bs[srow][scol + 4]  = make_uint2(b0.z, b0.w);
        *(uint2*)&Bs[srow][scol + 8]  = make_uint2(b1.x, b1.y);
        *(uint2*)&Bs[srow][scol + 12] = make_uint2(b1.z, b1.w);
        if (kt < 3) {
            int ko = (kt + 1) * 64;
            a0 = *(const uint4*)(Ap + ko);
            a1 = *(const uint4*)(Ap + ko + 8);
            b0 = *(const uint4*)(Bp + ko);
            b1 = *(const uint4*)(Bp + ko + 8);
        }
        __syncthreads();

        #pragma unroll
        for (int kb = 0; kb < 2; ++kb) {
            union { unsigned int u[4]; bf16x8 v; } af;
            {
                const uint2* p = (const uint2*)&As[wid * 16 + l15][kb * 32 + lk * 8];
                uint2 lo = p[0], hi = p[1];
                af.u[0] = lo.x; af.u[1] = lo.y; af.u[2] = hi.x; af.u[3] = hi.y;
            }
            #pragma unroll
            for (int ni = 0; ni < 4; ++ni) {
                union { unsigned int u[4]; bf16x8 v; } bf;
                const uint2* p = (const uint2*)&Bs[ni * 16 + l15][kb * 32 + lk * 8];
                uint2 lo = p[0], hi = p[1];
                bf.u[0] = lo.x; bf.u[1] = lo.y; bf.u[2] = hi.x; bf.u[3] = hi.y;
                acc[ni] = __builtin_amdgcn_mfma_f32_16x16x32_bf16(af.v, bf.v, acc[ni], 0, 0, 0);
            }
        }
    }

    // C/D layout: col = lane&15, row = (lane>>4)*4 + reg  [guide m89]
    float* outp = pp + (size_t)blockIdx.z * PSTR;
    #pragma unroll
    for (int ni = 0; ni < 4; ++ni) {
        int col = e0 + ni * 16 + l15;
        #pragma unroll
        for (int r = 0; r < 4; ++r) {
            int row = row0 + wid * 16 + lk * 4 + r;
            outp[(size_t)row * DD + col] = acc[ni][r];
        }
    }
}

// ---------------------------------------------------------------------------
// Kernel 2: logits, EXP-PRECOMPUTED staging + 4-WAY paired rcp. [r16 verbatim]
// Staging: EX = 2^(LOG2E2*(pp0+pp1+Wb)) (x-rows), EM = 2^(LOG2E2*(pp0+pp1)).
// Inner per 4 d's: D_k = fma(EX,EM,1);
//   sum_k V_k/D_k = (N01*P23 + N23*P01) / (P01*P23)
// Tile 32a x 64b x 64d, 2a x 4b micro-tile. LDS 26.4 KB.
// Grid (4, 32, 8) = 1024 blocks. 8 partial planes.
// ---------------------------------------------------------------------------
__global__ __launch_bounds__(256, 3) void logits_kernel(
    const float* __restrict__ pp, const float* __restrict__ Wb,
    const float* __restrict__ Vw, float* __restrict__ wpart)
{
    __shared__ __attribute__((aligned(16))) float xs[64][34];  // [d][a] = EX
    __shared__ __attribute__((aligned(16))) float ms[64][68];  // [d][b] = EM
    __shared__ __attribute__((aligned(16))) float vsh[64];

    int n  = blockIdx.z;
    int bt = blockIdx.x;          // 0..3 : 64 b-cols
    int at = blockIdx.y & 3;      // 0..3 : 32 a-rows
    int dc = blockIdx.y >> 2;     // 0..7 : 64-d chunk
    int tid = threadIdx.x;
    int ty = tid >> 4, tx = tid & 15;

    // ---- stage x-part: 32 rows x 64 d -> EX (sum 2 planes + bias, scale, exp2)
    {
        int r  = tid & 31;
        int c8 = (tid >> 5) * 8;
        size_t base = ((size_t)(n * LL0 + at * 32) + r) * DD + dc * 64 + c8;
        float4 p00 = *(const float4*)(pp + base);
        float4 p01 = *(const float4*)(pp + base + 4);
        float4 p10 = *(const float4*)(pp + PSTR + base);
        float4 p11 = *(const float4*)(pp + PSTR + base + 4);
        float4 w0  = *(const float4*)(Wb + dc * 64 + c8);
        float4 w1  = *(const float4*)(Wb + dc * 64 + c8 + 4);
        xs[c8 + 0][r] = fexp2(LOG2E2 * (p00.x + p10.x + w0.x));
        xs[c8 + 1][r] = fexp2(LOG2E2 * (p00.y + p10.y + w0.y));
        xs[c8 + 2][r] = fexp2(LOG2E2 * (p00.z + p10.z + w0.z));
        xs[c8 + 3][r] = fexp2(LOG2E2 * (p00.w + p10.w + w0.w));
        xs[c8 + 4][r] = fexp2(LOG2E2 * (p01.x + p11.x + w1.x));
        xs[c8 + 5][r] = fexp2(LOG2E2 * (p01.y + p11.y + w1.y));
        xs[c8 + 6][r] = fexp2(LOG2E2 * (p01.z + p11.z + w1.z));
        xs[c8 + 7][r] = fexp2(LOG2E2 * (p01.w + p11.w + w1.w));
    }
    // ---- stage m-part: 64 rows x 64 d -> EM
    {
        int r   = tid & 63;
        int c16 = (tid >> 6) * 16;
        size_t base = ((size_t)(NN * LL0 + n * LL1 + bt * 64) + r) * DD
                      + dc * 64 + c16;
        #pragma unroll
        for (int q = 0; q < 4; ++q) {
            float4 p0 = *(const float4*)(pp + base + q * 4);
            float4 p1 = *(const float4*)(pp + PSTR + base + q * 4);
            int c = c16 + q * 4;
            ms[c + 0][r] = fexp2(LOG2E2 * (p0.x + p1.x));
            ms[c + 1][r] = fexp2(LOG2E2 * (p0.y + p1.y));
            ms[c + 2][r] = fexp2(LOG2E2 * (p0.z + p1.z));
            ms[c + 3][r] = fexp2(LOG2E2 * (p0.w + p1.w));
        }
        if (tid < 16)
            *(float4*)&vsh[tid * 4] = *(const float4*)(Vw + dc * 64 + tid * 4);
    }
    __syncthreads();

    float acc[2][4] = {};

    #pragma unroll 4
    for (int kk = 0; kk < 64; kk += 4) {
        float2 xa0 = *(const float2*)&xs[kk + 0][ty * 2];
        float2 xa1 = *(const float2*)&xs[kk + 1][ty * 2];
        float2 xa2 = *(const float2*)&xs[kk + 2][ty * 2];
        float2 xa3 = *(const float2*)&xs[kk + 3][ty * 2];
        float4 mb0 = *(const float4*)&ms[kk + 0][tx * 4];
        float4 mb1 = *(const float4*)&ms[kk + 1][tx * 4];
        float4 mb2 = *(const float4*)&ms[kk + 2][tx * 4];
        float4 mb3 = *(const float4*)&ms[kk + 3][tx * 4];
        float4 vv  = *(const float4*)&vsh[kk];

        float ex[4][2] = {{xa0.x, xa0.y}, {xa1.x, xa1.y},
                          {xa2.x, xa2.y}, {xa3.x, xa3.y}};
        float fm[4][4] = {{mb0.x, mb0.y, mb0.z, mb0.w},
                          {mb1.x, mb1.y, mb1.z, mb1.w},
                          {mb2.x, mb2.y, mb2.z, mb2.w},
                          {mb3.x, mb3.y, mb3.z, mb3.w}};
        #pragma unroll
        for (int i = 0; i < 2; ++i) {
            #pragma unroll
            for (int j = 0; j < 4; ++j) {
                float D0 = fmaf(ex[0][i], fm[0][j], 1.0f);
                float D1 = fmaf(ex[1][i], fm[1][j], 1.0f);
                float D2 = fmaf(ex[2][i], fm[2][j], 1.0f);
                float D3 = fmaf(ex[3][i], fm[3][j], 1.0f);
                float P01 = D0 * D1, P23 = D2 * D3;
                float N01 = fmaf(vv.x, D1, vv.y * D0);
                float N23 = fmaf(vv.z, D3, vv.w * D2);
                float N   = fmaf(N01, P23, N23 * P01);
                acc[i][j] = fmaf(N, frcp(P01 * P23), acc[i][j]);
            }
        }
    }

    const size_t P = (size_t)NN * LL0 * LL1;
    float* wp = wpart + (size_t)dc * P
              + ((size_t)n * LL0 + at * 32 + ty * 2) * LL1 + bt * 64 + tx * 4;
    *(float4*)(wp)       = make_float4(acc[0][0], acc[0][1], acc[0][2], acc[0][3]);
    *(float4*)(wp + LL1) = make_float4(acc[1][0], acc[1][1], acc[1][2], acc[1][3]);
}

// ---------------------------------------------------------------------------
// Kernel 3: FUSED softmax + PV GEMM (r15-proven structure, 8 planes).
// Per block (n, a0-tile of 32, d0-tile of 64):
//   1. stage w[b][a]: sum 8 wpart planes, w = mask ? exp(-2*s8) : 0 (no max
//      pass: |logit| <= 2*sum|V| ~ 12, fp32-safe), row-sums -> rinv[a].
//   2. GEMM: v[a][d] = (sum_b w[b][a] * m[n,b,d]) * rinv[a].
// Redundant softmax across the 8 d0-tiles buys one less kernel launch +
// no dense-w round trip. LDS ~47 KB.
// Grid (8, 4, 8) = 256 blocks = 1.0/CU exact (same as the r16 vgemm).
// ---------------------------------------------------------------------------
__global__ __launch_bounds__(256, 3) void pv_kernel(
    const float* __restrict__ wpart, const int* __restrict__ mask,
    const float* __restrict__ m, float* __restrict__ out)
{
    __shared__ float wt[256][36];   // [b][a: 32+4]
    __shared__ float mt[32][68];    // [k][d: 64+4]
    __shared__ float rsum[32][9];
    __shared__ float rinv[32];

    const size_t P = (size_t)NN * LL0 * LL1;
    int n  = blockIdx.z;
    int a0 = blockIdx.y * 32;
    int d0 = blockIdx.x * 64;
    int tid = threadIdx.x;
    int ty = tid >> 4, tx = tid & 15;

    // ---- stage w: 256 b x 32 a (sum 8 planes, exp, mask)
    {
        int a = tid & 31;
        int g = tid >> 5;             // 0..7 -> b-range g*32..+31
        const float* wp0 = wpart + ((size_t)(n * LL0) + a0 + a) * LL1 + g * 32;
        const int*   mk  = mask + n * LL1 + g * 32;
        float ls = 0.f;
        #pragma unroll
        for (int q = 0; q < 8; ++q) {
            float4 s4 = make_float4(0.f, 0.f, 0.f, 0.f);
            #pragma unroll
            for (int p = 0; p < 8; ++p) {
                float4 pv = *(const float4*)(wp0 + (size_t)p * P + q * 4);
                s4.x += pv.x; s4.y += pv.y; s4.z += pv.z; s4.w += pv.w;
            }
            int4 mv = *(const int4*)(mk + q * 4);
            float w0 = mv.x ? __expf(-2.f * s4.x) : 0.f;
            float w1 = mv.y ? __expf(-2.f * s4.y) : 0.f;
            float w2 = mv.z ? __expf(-2.f * s4.z) : 0.f;
            float w3 = mv.w ? __expf(-2.f * s4.w) : 0.f;
            int b = g * 32 + q * 4;
            wt[b + 0][a] = w0; wt[b + 1][a] = w1;
            wt[b + 2][a] = w2; wt[b + 3][a] = w3;
            ls += w0 + w1 + w2 + w3;
        }
        rsum[a][g] = ls;
    }
    __syncthreads();
    if (tid < 32) {
        float s = 0.f;
        #pragma unroll
        for (int g = 0; g < 8; ++g) s += rsum[tid][g];
        rinv[tid] = frcp(s);
    }
    __syncthreads();

    // ---- GEMM over b (k = 256), mt staged per 32-chunk
    const float* mrow = m + (size_t)n * LL1 * DD;
    float acc[2][4] = {};
    for (int k0 = 0; k0 < LL1; k0 += 32) {
        {
            int r  = tid >> 3;            // k-row 0..31
            int c8 = (tid & 7) * 8;       // d 0..56
            const float* src = mrow + (size_t)(k0 + r) * DD + d0 + c8;
            *(float4*)&mt[r][c8]     = *(const float4*)(src);
            *(float4*)&mt[r][c8 + 4] = *(const float4*)(src + 4);
        }
        __syncthreads();
        #pragma unroll 8
        for (int kk = 0; kk < 32; ++kk) {
            float2 av = *(const float2*)&wt[k0 + kk][ty * 2];
            float4 bv = *(const float4*)&mt[kk][tx * 4];
            acc[0][0] = fmaf(av.x, bv.x, acc[0][0]);
            acc[0][1] = fmaf(av.x, bv.y, acc[0][1]);
            acc[0][2] = fmaf(av.x, bv.z, acc[0][2]);
            acc[0][3] = fmaf(av.x, bv.w, acc[0][3]);
            acc[1][0] = fmaf(av.y, bv.x, acc[1][0]);
            acc[1][1] = fmaf(av.y, bv.y, acc[1][1]);
            acc[1][2] = fmaf(av.y, bv.z, acc[1][2]);
            acc[1][3] = fmaf(av.y, bv.w, acc[1][3]);
        }
        __syncthreads();
    }

    float r0 = rinv[ty * 2], r1 = rinv[ty * 2 + 1];
    float* op = out + ((size_t)n * LL0 + a0 + ty * 2) * DD + d0 + tx * 4;
    *(float4*)(op)      = make_float4(acc[0][0] * r0, acc[0][1] * r0,
                                      acc[0][2] * r0, acc[0][3] * r0);
    *(float4*)(op + DD) = make_float4(acc[1][0] * r1, acc[1][1] * r1,
                                      acc[1][2] * r1, acc[1][3] * r1);
}

extern "C" void kernel_launch(void* const* d_in, const int* in_sizes, int n_in,
                              void* d_out, int out_size, void* d_ws, size_t ws_size,
                              hipStream_t stream) {
    const float* x    = (const float*)d_in[0];
    const float* m    = (const float*)d_in[1];
    const int*   mask = (const int*)d_in[2];
    const float* W_w  = (const float*)d_in[3];
    const float* W_b  = (const float*)d_in[4];
    const float* V_w  = (const float*)d_in[5];
    const float* V_b  = (const float*)d_in[6];
    (void)V_b; // additive constant — cancels under softmax shift-invariance
    float* out = (float*)d_out;

    // Workspace (floats):
    //   pp    : 2 * PSTR             = 3,145,728
    //   wpart : 8 * 8*128*256        = 2,097,152
    //   A16   : 3072*512 bf16        =   786,432  float-equiv
    //   W16   : 512*1024 bf16        =   262,144  float-equiv
    // Total: 6,291,456 floats = 25.2 MB
    float* pp    = (float*)d_ws;
    float* wpart = pp + 2 * PSTR;
    unsigned short* A16 = (unsigned short*)(wpart + (size_t)8 * NN * LL0 * LL1);
    unsigned short* W16 = A16 + (size_t)3072 * 512;

    cvt_kernel<<<dim3(2048), 256, 0, stream>>>(x, m, W_w, A16, W16);
    mfma_proj_kernel<<<dim3(8, 48, 2), 256, 0, stream>>>(A16, W16, pp);
    logits_kernel<<<dim3(4, 32, 8), 256, 0, stream>>>(pp, W_b, V_w, wpart);
    pv_kernel<<<dim3(8, 4, 8), 256, 0, stream>>>(wpart, mask, m, out);
}

// Round 18
// 49.185 us; speedup vs baseline: 1.7340x; 1.7340x over previous
//
#include <hip/hip_runtime.h>
#include <hip/hip_bf16.h>

#define DD 512
#define NN 8
#define LL0 128
#define LL1 256

// 2 * log2(e): pre-scale so tanh(t) needs only v_exp_f32 (2^x).
#define LOG2E2 2.8853900817779268f

// split-K partial plane stride (floats): 3072 rows x 512 e
#define PSTR ((size_t)3072 * 512)

typedef float f32x4 __attribute__((ext_vector_type(4)));
typedef __bf16 bf16x8 __attribute__((ext_vector_type(8)));

__device__ __forceinline__ float fexp2(float x) {
#if __has_builtin(__builtin_amdgcn_exp2f)
    return __builtin_amdgcn_exp2f(x);
#else
    float r; asm("v_exp_f32 %0, %1" : "=v"(r) : "v"(x)); return r;
#endif
}
__device__ __forceinline__ float frcp(float x) {
#if __has_builtin(__builtin_amdgcn_rcpf)
    return __builtin_amdgcn_rcpf(x);
#else
    float r; asm("v_rcp_f32 %0, %1" : "=v"(r) : "v"(x)); return r;
#endif
}

// fp32 -> bf16 round-to-nearest-even (normals; inputs are well-scaled).
__device__ __forceinline__ unsigned short f2bf(float f) {
    unsigned int u = __float_as_uint(f);
    u += 0x7fffu + ((u >> 16) & 1u);
    return (unsigned short)(u >> 16);
}

// ---------------------------------------------------------------------------
// Kernel 0: convert x|m -> A16[3072][512] bf16, W -> W16[512][1024] bf16.
// ---------------------------------------------------------------------------
__global__ __launch_bounds__(256) void cvt_kernel(
    const float* __restrict__ x, const float* __restrict__ m,
    const float* __restrict__ W,
    unsigned short* __restrict__ A16, unsigned short* __restrict__ W16)
{
    size_t i4 = ((size_t)blockIdx.x * 256 + threadIdx.x) * 4;
    const float* src;
    unsigned short* dst;
    if (i4 < (size_t)3072 * 512) {                 // A-part (x then m)
        src = (i4 < (size_t)1024 * 512) ? x + i4 : m + (i4 - (size_t)1024 * 512);
        dst = A16 + i4;
    } else {                                       // W-part
        size_t j = i4 - (size_t)3072 * 512;
        src = W + j; dst = W16 + j;
    }
    float4 v = *(const float4*)src;
    ushort4 o = make_ushort4(f2bf(v.x), f2bf(v.y), f2bf(v.z), f2bf(v.w));
    *(ushort4*)dst = o;
}

// ---------------------------------------------------------------------------
// Kernel 1: MFMA bf16 projection GEMM, split-K=2.
//   pp[kz][row][e] = sum_{k in half kz} A16[row][k] * W16[e][koff+k]
// 64x64 tile, K-step 64, 4 waves; 68-short row pad (136 B) -> b64 fragment
// reads bank-optimal. Grid (8, 48, 2) = 768 blocks = 3.0/CU exact.
// ---------------------------------------------------------------------------
__global__ __launch_bounds__(256, 3) void mfma_proj_kernel(
    const unsigned short* __restrict__ A16, const unsigned short* __restrict__ W16,
    float* __restrict__ pp)
{
    __shared__ unsigned short As[64][68];
    __shared__ unsigned short Bs[64][68];

    int e0   = blockIdx.x * 64;
    int row0 = blockIdx.y * 64;
    int kb0  = blockIdx.z * 256;       // K-half base
    bool isx = row0 < (NN * LL0);
    int koff = isx ? 0 : DD;

    int tid  = threadIdx.x;
    int wid  = tid >> 6;               // wave 0..3 -> rows wid*16..+15
    int lane = tid & 63;
    int l15  = lane & 15, lk = lane >> 4;   // lk 0..3

    int srow = tid >> 2;               // staging row 0..63
    int scol = (tid & 3) * 16;         // staging k-col (bf16 units)

    const unsigned short* Ap = A16 + (size_t)(row0 + srow) * DD + kb0 + scol;
    const unsigned short* Bp = W16 + (size_t)(e0 + srow) * (2 * DD) + koff + kb0 + scol;

    uint4 a0 = *(const uint4*)(Ap);
    uint4 a1 = *(const uint4*)(Ap + 8);
    uint4 b0 = *(const uint4*)(Bp);
    uint4 b1 = *(const uint4*)(Bp + 8);

    f32x4 acc[4] = {};

    for (int kt = 0; kt < 4; ++kt) {
        if (kt) __syncthreads();
        *(uint2*)&As[srow][scol + 0]  = make_uint2(a0.x, a0.y);
        *(uint2*)&As[srow][scol + 4]  = make_uint2(a0.z, a0.w);
        *(uint2*)&As[srow][scol + 8]  = make_uint2(a1.x, a1.y);
        *(uint2*)&As[srow][scol + 12] = make_uint2(a1.z, a1.w);
        *(uint2*)&Bs[srow][scol + 0]  = make_uint2(b0.x, b0.y);
        *(uint2*)&Bs[srow][scol + 4]  = make_uint2(b0.z, b0.w);
        *(uint2*)&Bs[srow][scol + 8]  = make_uint2(b1.x, b1.y);
        *(uint2*)&Bs[srow][scol + 12] = make_uint2(b1.z, b1.w);
        if (kt < 3) {
            int ko = (kt + 1) * 64;
            a0 = *(const uint4*)(Ap + ko);
            a1 = *(const uint4*)(Ap + ko + 8);
            b0 = *(const uint4*)(Bp + ko);
            b1 = *(const uint4*)(Bp + ko + 8);
        }
        __syncthreads();

        #pragma unroll
        for (int kb = 0; kb < 2; ++kb) {
            union { unsigned int u[4]; bf16x8 v; } af;
            {
                const uint2* p = (const uint2*)&As[wid * 16 + l15][kb * 32 + lk * 8];
                uint2 lo = p[0], hi = p[1];
                af.u[0] = lo.x; af.u[1] = lo.y; af.u[2] = hi.x; af.u[3] = hi.y;
            }
            #pragma unroll
            for (int ni = 0; ni < 4; ++ni) {
                union { unsigned int u[4]; bf16x8 v; } bf;
                const uint2* p = (const uint2*)&Bs[ni * 16 + l15][kb * 32 + lk * 8];
                uint2 lo = p[0], hi = p[1];
                bf.u[0] = lo.x; bf.u[1] = lo.y; bf.u[2] = hi.x; bf.u[3] = hi.y;
                acc[ni] = __builtin_amdgcn_mfma_f32_16x16x32_bf16(af.v, bf.v, acc[ni], 0, 0, 0);
            }
        }
    }

    // C/D layout: col = lane&15, row = (lane>>4)*4 + reg  [guide m89]
    float* outp = pp + (size_t)blockIdx.z * PSTR;
    #pragma unroll
    for (int ni = 0; ni < 4; ++ni) {
        int col = e0 + ni * 16 + l15;
        #pragma unroll
        for (int r = 0; r < 4; ++r) {
            int row = row0 + wid * 16 + lk * 4 + r;
            outp[(size_t)row * DD + col] = acc[ni][r];
        }
    }
}

// ---------------------------------------------------------------------------
// Kernel 2: logits, EXP-PRECOMPUTED staging + 4-WAY paired rcp.
// Staging: EX = 2^(LOG2E2*(pp0+pp1+Wb)) (x-rows), EM = 2^(LOG2E2*(pp0+pp1)).
// Inner per 4 d's: D_k = fma(EX,EM,1);
//   sum_k V_k/D_k = (N01*P23 + N23*P01) / (P01*P23)
// Tile 32a x 64b x 64d, 2a x 4b micro-tile. LDS 26.4 KB.
// Grid (4, 32, 8) = 1024 blocks. 8 partial planes.
// ---------------------------------------------------------------------------
__global__ __launch_bounds__(256, 3) void logits_kernel(
    const float* __restrict__ pp, const float* __restrict__ Wb,
    const float* __restrict__ Vw, float* __restrict__ wpart)
{
    __shared__ __attribute__((aligned(16))) float xs[64][34];  // [d][a] = EX
    __shared__ __attribute__((aligned(16))) float ms[64][68];  // [d][b] = EM
    __shared__ __attribute__((aligned(16))) float vsh[64];

    int n  = blockIdx.z;
    int bt = blockIdx.x;          // 0..3 : 64 b-cols
    int at = blockIdx.y & 3;      // 0..3 : 32 a-rows
    int dc = blockIdx.y >> 2;     // 0..7 : 64-d chunk
    int tid = threadIdx.x;
    int ty = tid >> 4, tx = tid & 15;

    // ---- stage x-part: 32 rows x 64 d -> EX (sum 2 planes + bias, scale, exp2)
    {
        int r  = tid & 31;
        int c8 = (tid >> 5) * 8;
        size_t base = ((size_t)(n * LL0 + at * 32) + r) * DD + dc * 64 + c8;
        float4 p00 = *(const float4*)(pp + base);
        float4 p01 = *(const float4*)(pp + base + 4);
        float4 p10 = *(const float4*)(pp + PSTR + base);
        float4 p11 = *(const float4*)(pp + PSTR + base + 4);
        float4 w0  = *(const float4*)(Wb + dc * 64 + c8);
        float4 w1  = *(const float4*)(Wb + dc * 64 + c8 + 4);
        xs[c8 + 0][r] = fexp2(LOG2E2 * (p00.x + p10.x + w0.x));
        xs[c8 + 1][r] = fexp2(LOG2E2 * (p00.y + p10.y + w0.y));
        xs[c8 + 2][r] = fexp2(LOG2E2 * (p00.z + p10.z + w0.z));
        xs[c8 + 3][r] = fexp2(LOG2E2 * (p00.w + p10.w + w0.w));
        xs[c8 + 4][r] = fexp2(LOG2E2 * (p01.x + p11.x + w1.x));
        xs[c8 + 5][r] = fexp2(LOG2E2 * (p01.y + p11.y + w1.y));
        xs[c8 + 6][r] = fexp2(LOG2E2 * (p01.z + p11.z + w1.z));
        xs[c8 + 7][r] = fexp2(LOG2E2 * (p01.w + p11.w + w1.w));
    }
    // ---- stage m-part: 64 rows x 64 d -> EM
    {
        int r   = tid & 63;
        int c16 = (tid >> 6) * 16;
        size_t base = ((size_t)(NN * LL0 + n * LL1 + bt * 64) + r) * DD
                      + dc * 64 + c16;
        #pragma unroll
        for (int q = 0; q < 4; ++q) {
            float4 p0 = *(const float4*)(pp + base + q * 4);
            float4 p1 = *(const float4*)(pp + PSTR + base + q * 4);
            int c = c16 + q * 4;
            ms[c + 0][r] = fexp2(LOG2E2 * (p0.x + p1.x));
            ms[c + 1][r] = fexp2(LOG2E2 * (p0.y + p1.y));
            ms[c + 2][r] = fexp2(LOG2E2 * (p0.z + p1.z));
            ms[c + 3][r] = fexp2(LOG2E2 * (p0.w + p1.w));
        }
        if (tid < 16)
            *(float4*)&vsh[tid * 4] = *(const float4*)(Vw + dc * 64 + tid * 4);
    }
    __syncthreads();

    float acc[2][4] = {};

    #pragma unroll 4
    for (int kk = 0; kk < 64; kk += 4) {
        float2 xa0 = *(const float2*)&xs[kk + 0][ty * 2];
        float2 xa1 = *(const float2*)&xs[kk + 1][ty * 2];
        float2 xa2 = *(const float2*)&xs[kk + 2][ty * 2];
        float2 xa3 = *(const float2*)&xs[kk + 3][ty * 2];
        float4 mb0 = *(const float4*)&ms[kk + 0][tx * 4];
        float4 mb1 = *(const float4*)&ms[kk + 1][tx * 4];
        float4 mb2 = *(const float4*)&ms[kk + 2][tx * 4];
        float4 mb3 = *(const float4*)&ms[kk + 3][tx * 4];
        float4 vv  = *(const float4*)&vsh[kk];

        float ex[4][2] = {{xa0.x, xa0.y}, {xa1.x, xa1.y},
                          {xa2.x, xa2.y}, {xa3.x, xa3.y}};
        float fm[4][4] = {{mb0.x, mb0.y, mb0.z, mb0.w},
                          {mb1.x, mb1.y, mb1.z, mb1.w},
                          {mb2.x, mb2.y, mb2.z, mb2.w},
                          {mb3.x, mb3.y, mb3.z, mb3.w}};
        #pragma unroll
        for (int i = 0; i < 2; ++i) {
            #pragma unroll
            for (int j = 0; j < 4; ++j) {
                float D0 = fmaf(ex[0][i], fm[0][j], 1.0f);
                float D1 = fmaf(ex[1][i], fm[1][j], 1.0f);
                float D2 = fmaf(ex[2][i], fm[2][j], 1.0f);
                float D3 = fmaf(ex[3][i], fm[3][j], 1.0f);
                float P01 = D0 * D1, P23 = D2 * D3;
                float N01 = fmaf(vv.x, D1, vv.y * D0);
                float N23 = fmaf(vv.z, D3, vv.w * D2);
                float N   = fmaf(N01, P23, N23 * P01);
                acc[i][j] = fmaf(N, frcp(P01 * P23), acc[i][j]);
            }
        }
    }

    const size_t P = (size_t)NN * LL0 * LL1;
    float* wp = wpart + (size_t)dc * P
              + ((size_t)n * LL0 + at * 32 + ty * 2) * LL1 + bt * 64 + tx * 4;
    *(float4*)(wp)       = make_float4(acc[0][0], acc[0][1], acc[0][2], acc[0][3]);
    *(float4*)(wp + LL1) = make_float4(acc[1][0], acc[1][1], acc[1][2], acc[1][3]);
}

// ---------------------------------------------------------------------------
// Kernel 3: masked softmax over b, 8 partial planes, no max pass
// (logit = -2*s8 bounded by +-2*sum|V| ~ 45: exp cannot over/underflow fp32).
// Masked -> exactly 0. Dense write into plane 0.
// ---------------------------------------------------------------------------
__global__ __launch_bounds__(256) void softmax_kernel(
    float* __restrict__ wpart, const int* __restrict__ mask)
{
    __shared__ float red2[4];
    const size_t P = (size_t)NN * LL0 * LL1;
    int row = blockIdx.x;          // n*L0 + a
    int n = row >> 7;
    int b = threadIdx.x;
    size_t idx = (size_t)row * LL1 + b;

    float s8 = 0.f;
    #pragma unroll
    for (int p = 0; p < 8; ++p) s8 += wpart[idx + (size_t)p * P];
    float w = -2.0f * s8;

    float e = (mask[n * LL1 + b] != 0) ? __expf(w) : 0.f;
    float s = e;
    #pragma unroll
    for (int off = 32; off; off >>= 1) s += __shfl_xor(s, off);
    int wv = threadIdx.x >> 6;
    if ((threadIdx.x & 63) == 0) red2[wv] = s;
    __syncthreads();
    s = red2[0] + red2[1] + red2[2] + red2[3];

    wpart[idx] = e / s;            // dense write into plane 0 (reads done first)
}

// ---------------------------------------------------------------------------
// Kernel 4: v[n,a,d] = sum_b w[n,a,b] * m[n,b,d].
// ---------------------------------------------------------------------------
__global__ __launch_bounds__(256, 4) void vgemm_kernel(
    const float* __restrict__ wbuf, const float* __restrict__ m,
    float* __restrict__ out)
{
    __shared__ float wt[32][36];   // [k][a: 32+4]
    __shared__ float mt[32][68];   // [k][d: 64+4]

    int n  = blockIdx.z;
    int a0 = blockIdx.y * 32;
    int d0 = blockIdx.x * 64;
    int tid = threadIdx.x;
    int ty = tid >> 4, tx = tid & 15;

    const float* wrow = wbuf + ((size_t)n * LL0 + a0) * LL1;
    const float* mrow = m + (size_t)n * LL1 * DD;

    float acc[2][4] = {};
    for (int k0 = 0; k0 < LL1; k0 += 32) {
        {
            int r  = tid >> 3;            // a-row 0..31
            int c4 = (tid & 7) * 4;       // k 0..28
            float4 wv = *(const float4*)(wrow + (size_t)r * LL1 + k0 + c4);
            wt[c4 + 0][r] = wv.x; wt[c4 + 1][r] = wv.y;
            wt[c4 + 2][r] = wv.z; wt[c4 + 3][r] = wv.w;
        }
        {
            int r  = tid >> 3;            // k-row 0..31
            int c8 = (tid & 7) * 8;       // d 0..56
            const float* src = mrow + (size_t)(k0 + r) * DD + d0 + c8;
            *(float4*)&mt[r][c8]     = *(const float4*)(src);
            *(float4*)&mt[r][c8 + 4] = *(const float4*)(src + 4);
        }
        __syncthreads();
        #pragma unroll 8
        for (int kk = 0; kk < 32; ++kk) {
            float2 av = *(const float2*)&wt[kk][ty * 2];
            float4 bv = *(const float4*)&mt[kk][tx * 4];
            acc[0][0] = fmaf(av.x, bv.x, acc[0][0]);
            acc[0][1] = fmaf(av.x, bv.y, acc[0][1]);
            acc[0][2] = fmaf(av.x, bv.z, acc[0][2]);
            acc[0][3] = fmaf(av.x, bv.w, acc[0][3]);
            acc[1][0] = fmaf(av.y, bv.x, acc[1][0]);
            acc[1][1] = fmaf(av.y, bv.y, acc[1][1]);
            acc[1][2] = fmaf(av.y, bv.z, acc[1][2]);
            acc[1][3] = fmaf(av.y, bv.w, acc[1][3]);
        }
        __syncthreads();
    }
    float* op = out + ((size_t)n * LL0 + a0 + ty * 2) * DD + d0 + tx * 4;
    *(float4*)(op)      = make_float4(acc[0][0], acc[0][1], acc[0][2], acc[0][3]);
    *(float4*)(op + DD) = make_float4(acc[1][0], acc[1][1], acc[1][2], acc[1][3]);
}

extern "C" void kernel_launch(void* const* d_in, const int* in_sizes, int n_in,
                              void* d_out, int out_size, void* d_ws, size_t ws_size,
                              hipStream_t stream) {
    const float* x    = (const float*)d_in[0];
    const float* m    = (const float*)d_in[1];
    const int*   mask = (const int*)d_in[2];
    const float* W_w  = (const float*)d_in[3];
    const float* W_b  = (const float*)d_in[4];
    const float* V_w  = (const float*)d_in[5];
    const float* V_b  = (const float*)d_in[6];
    (void)V_b; // additive constant — cancels under softmax shift-invariance
    float* out = (float*)d_out;

    // Workspace (floats):
    //   pp    : 2 * PSTR             = 3,145,728
    //   wpart : 8 * 8*128*256        = 2,097,152  (plane 0 reused as w)
    //   A16   : 3072*512 bf16        =   786,432  float-equiv
    //   W16   : 512*1024 bf16        =   262,144  float-equiv
    // Total: 6,291,456 floats = 25.2 MB
    float* pp    = (float*)d_ws;
    float* wpart = pp + 2 * PSTR;
    unsigned short* A16 = (unsigned short*)(wpart + (size_t)8 * NN * LL0 * LL1);
    unsigned short* W16 = A16 + (size_t)3072 * 512;

    cvt_kernel<<<dim3(2048), 256, 0, stream>>>(x, m, W_w, A16, W16);
    mfma_proj_kernel<<<dim3(8, 48, 2), 256, 0, stream>>>(A16, W16, pp);
    logits_kernel<<<dim3(4, 32, 8), 256, 0, stream>>>(pp, W_b, V_w, wpart);
    softmax_kernel<<<dim3(1024), 256, 0, stream>>>(wpart, mask);
    vgemm_kernel<<<dim3(8, 4, 8), 256, 0, stream>>>(wpart, m, out);
}